// Round 1
// baseline (1033.445 us; speedup 1.0000x reference)
//
#include <hip/hip_runtime.h>
#include <hip/hip_bf16.h>

#define Bdim 2
#define Hdim 8
#define Sdim 2048
#define Ddim 64

typedef short bf16x8 __attribute__((ext_vector_type(8)));
typedef float f32x4 __attribute__((ext_vector_type(4)));

// float -> bf16 bits, round-to-nearest-even
static __device__ __forceinline__ short f2bf(float x) {
  unsigned u = __builtin_bit_cast(unsigned, x);
  unsigned r = (u + 0x7fffu + ((u >> 16) & 1u)) >> 16;
  return (short)r;
}

static __device__ __forceinline__ bf16x8 pack8(float4 a, float4 b, float s) {
  bf16x8 r;
  r[0] = f2bf(a.x * s); r[1] = f2bf(a.y * s);
  r[2] = f2bf(a.z * s); r[3] = f2bf(a.w * s);
  r[4] = f2bf(b.x * s); r[5] = f2bf(b.y * s);
  r[6] = f2bf(b.z * s); r[7] = f2bf(b.w * s);
  return r;
}

// One block = (b, h, 64-row q-tile). 4 waves x 16 rows each.
// Sweep 1: row sums of exp(blended masked logits) -> 1/l
// Sweep 2: recompute, write normalized attn, PV-accumulate via MFMA.
__global__ __launch_bounds__(256) void fused_attn(
    const float* __restrict__ qp, const float* __restrict__ kp,
    const float* __restrict__ vp, const float* __restrict__ covp,
    const float* __restrict__ lamp, const int* __restrict__ maskp,
    float* __restrict__ outO, float* __restrict__ outA)
{
  // Vt[d][t_local] bf16, stride 40 (80B rows: 16B-aligned b128 reads, banks spread)
  __shared__ __align__(16) short Vt[64][40];
  // Per-wave P stash [row][t_local], stride 40
  __shared__ __align__(16) short Pl[4][16][40];

  const int tid  = threadIdx.x;
  const int wv   = tid >> 6;
  const int lane = tid & 63;
  const int quad = lane >> 4;
  const int l15  = lane & 15;

  // swizzle: h = bid%8 -> all q-tiles of a head land on one XCD (K/V L2 reuse)
  const int bid = blockIdx.x;
  const int h  = bid & 7;
  const int qt = (bid >> 3) & 31;
  const int b  = bid >> 8;

  const float lam   = lamp[h];
  const float w_qk  = 1.0f / (lam + 1.0f);
  const float w_cov = lam / (lam + 1.0f);
  const float qscale = w_qk * 0.125f;   // fold 1/TEMPERATURE and w_qk into Q

  const int q0 = qt * 64 + wv * 16;     // this wave's first q-row
  const int bh = b * Hdim + h;

  const float* qbase = qp + ((size_t)bh * Sdim + q0) * Ddim;
  const float* kbase = kp + (size_t)bh * Sdim * Ddim;
  const float* vbase = vp + (size_t)bh * Sdim * Ddim;
  const float* covb  = covp + ((size_t)b * Sdim + q0) * Sdim;
  const int*   mb    = maskp + ((size_t)b * Sdim + q0) * Sdim;
  float* oA = outA + ((size_t)bh * Sdim + q0) * (size_t)Sdim;
  float* oO = outO + ((size_t)bh * Sdim + q0) * Ddim;

  // A-operand fragments for Q (16 rows x 64 k), pre-scaled by w_qk/8.
  // layout: A[m=lane&15][k = quad*8 + j]
  bf16x8 aq0, aq1;
  {
    const float* qr = qbase + l15 * Ddim + quad * 8;
    float4 x0 = *(const float4*)(qr);
    float4 x1 = *(const float4*)(qr + 4);
    aq0 = pack8(x0, x1, qscale);
    float4 y0 = *(const float4*)(qr + 32);
    float4 y1 = *(const float4*)(qr + 36);
    aq1 = pack8(y0, y1, qscale);
  }

  // ---------------- Sweep 1: row sums ----------------
  float lsum[4] = {0.f, 0.f, 0.f, 0.f};
  for (int t0 = 0; t0 < Sdim; t0 += 32) {
    f32x4 acc[2];
#pragma unroll
    for (int n = 0; n < 2; ++n) {
      // B-operand: B[k=d][n=t]; lane reads K[t0+n*16+l15][quad*8 + j]
      const float* kr = kbase + (size_t)(t0 + n * 16 + l15) * Ddim + quad * 8;
      float4 x0 = *(const float4*)(kr);
      float4 x1 = *(const float4*)(kr + 4);
      float4 y0 = *(const float4*)(kr + 32);
      float4 y1 = *(const float4*)(kr + 36);
      bf16x8 b0 = pack8(x0, x1, 1.0f);
      bf16x8 b1 = pack8(y0, y1, 1.0f);
      f32x4 a = {0.f, 0.f, 0.f, 0.f};
      a = __builtin_amdgcn_mfma_f32_16x16x32_bf16(aq0, b0, a, 0, 0, 0);
      a = __builtin_amdgcn_mfma_f32_16x16x32_bf16(aq1, b1, a, 0, 0, 0);
      acc[n] = a;
    }
#pragma unroll
    for (int n = 0; n < 2; ++n) {
      const int col = t0 + n * 16 + l15;
#pragma unroll
      for (int r = 0; r < 4; ++r) {
        const int row = quad * 4 + r;           // C/D layout row
        float c = covb[row * Sdim + col];
        int   m = mb[row * Sdim + col];
        float logit = acc[n][r] + w_cov * c;
        float p = m ? __expf(logit) : 0.0f;     // no max-sub needed: |logit| small
        lsum[r] += p;
      }
    }
  }
  // reduce across the 16 lanes of each quad-group (same rows)
  float rinv[4];
#pragma unroll
  for (int r = 0; r < 4; ++r) {
    float s = lsum[r];
    s += __shfl_xor(s, 1, 16);
    s += __shfl_xor(s, 2, 16);
    s += __shfl_xor(s, 4, 16);
    s += __shfl_xor(s, 8, 16);
    rinv[r] = 1.0f / s;
  }

  // ---------------- Sweep 2: write attn + PV ----------------
  f32x4 oacc[4];
#pragma unroll
  for (int n = 0; n < 4; ++n) oacc[n] = (f32x4){0.f, 0.f, 0.f, 0.f};

  for (int t0 = 0; t0 < Sdim; t0 += 32) {
    __syncthreads();   // previous iteration's LDS reads complete
    {
      // cooperative V tile load: V[t0+tt][d0..d0+7] -> Vt[d][tt] (transposed, bf16)
      const int tt = tid & 31;
      const int d0 = (tid >> 5) * 8;
      const float* vr = vbase + (size_t)(t0 + tt) * Ddim + d0;
      float4 x0 = *(const float4*)vr;
      float4 x1 = *(const float4*)(vr + 4);
      Vt[d0 + 0][tt] = f2bf(x0.x);
      Vt[d0 + 1][tt] = f2bf(x0.y);
      Vt[d0 + 2][tt] = f2bf(x0.z);
      Vt[d0 + 3][tt] = f2bf(x0.w);
      Vt[d0 + 4][tt] = f2bf(x1.x);
      Vt[d0 + 5][tt] = f2bf(x1.y);
      Vt[d0 + 6][tt] = f2bf(x1.z);
      Vt[d0 + 7][tt] = f2bf(x1.w);
    }

    f32x4 acc[2];
#pragma unroll
    for (int n = 0; n < 2; ++n) {
      const float* kr = kbase + (size_t)(t0 + n * 16 + l15) * Ddim + quad * 8;
      float4 x0 = *(const float4*)(kr);
      float4 x1 = *(const float4*)(kr + 4);
      float4 y0 = *(const float4*)(kr + 32);
      float4 y1 = *(const float4*)(kr + 36);
      bf16x8 b0 = pack8(x0, x1, 1.0f);
      bf16x8 b1 = pack8(y0, y1, 1.0f);
      f32x4 a = {0.f, 0.f, 0.f, 0.f};
      a = __builtin_amdgcn_mfma_f32_16x16x32_bf16(aq0, b0, a, 0, 0, 0);
      a = __builtin_amdgcn_mfma_f32_16x16x32_bf16(aq1, b1, a, 0, 0, 0);
      acc[n] = a;
    }
#pragma unroll
    for (int n = 0; n < 2; ++n) {
      const int col = t0 + n * 16 + l15;
#pragma unroll
      for (int r = 0; r < 4; ++r) {
        const int row = quad * 4 + r;
        float c = covb[row * Sdim + col];
        int   m = mb[row * Sdim + col];
        float logit = acc[n][r] + w_cov * c;
        float p = m ? __expf(logit) : 0.0f;
        p *= rinv[r];                                    // normalized attn value
        __builtin_nontemporal_store(p, &oA[(size_t)row * Sdim + col]);
        Pl[wv][row][n * 16 + l15] = f2bf(p);             // stash for PV A-frag
      }
    }
    __syncthreads();   // Vt + Pl visible

    // P in A-layout: A[m=l15][k=quad*8+j] ; V in B-layout: B[k=t][n=d]=Vt[d][k]
    bf16x8 pa = *(const bf16x8*)&Pl[wv][l15][quad * 8];
#pragma unroll
    for (int n = 0; n < 4; ++n) {
      bf16x8 bv = *(const bf16x8*)&Vt[n * 16 + l15][quad * 8];
      oacc[n] = __builtin_amdgcn_mfma_f32_16x16x32_bf16(pa, bv, oacc[n], 0, 0, 0);
    }
  }

  // epilogue: C/D layout row=quad*4+r, col=n*16+l15
#pragma unroll
  for (int n = 0; n < 4; ++n) {
#pragma unroll
    for (int r = 0; r < 4; ++r) {
      const int row = quad * 4 + r;
      __builtin_nontemporal_store(oacc[n][r], &oO[row * Ddim + n * 16 + l15]);
    }
  }
}

extern "C" void kernel_launch(void* const* d_in, const int* in_sizes, int n_in,
                              void* d_out, int out_size, void* d_ws, size_t ws_size,
                              hipStream_t stream) {
  const float* q    = (const float*)d_in[0];
  const float* k    = (const float*)d_in[1];
  const float* v    = (const float*)d_in[2];
  const float* cov  = (const float*)d_in[3];
  const float* lam  = (const float*)d_in[4];
  const int*   mask = (const int*)d_in[5];
  float* outO = (float*)d_out;
  float* outA = outO + (size_t)Bdim * Hdim * Sdim * Ddim;

  dim3 grid(Bdim * Hdim * (Sdim / 64));   // 512 blocks
  fused_attn<<<grid, 256, 0, stream>>>(q, k, v, cov, lam, mask, outO, outA);
}

// Round 3
// 705.553 us; speedup vs baseline: 1.4647x; 1.4647x over previous
//
#include <hip/hip_runtime.h>

#define Bdim 2
#define Hdim 8
#define Sdim 2048
#define Ddim 64
#define PSTR 2056   // P row stride in shorts: +8 pad breaks 16-way bank aliasing

typedef short bf16x8 __attribute__((ext_vector_type(8)));
typedef short bf16x4 __attribute__((ext_vector_type(4)));
typedef float f32x4 __attribute__((ext_vector_type(4)));

// float -> bf16 bits, round-to-nearest-even
static __device__ __forceinline__ short f2bf(float x) {
  unsigned u = __builtin_bit_cast(unsigned, x);
  unsigned r = (u + 0x7fffu + ((u >> 16) & 1u)) >> 16;
  return (short)r;
}
static __device__ __forceinline__ float bf2f(short x) {
  unsigned u = ((unsigned)(unsigned short)x) << 16;
  return __builtin_bit_cast(float, u);
}
static __device__ __forceinline__ bf16x8 pack8(float4 a, float4 b, float s) {
  bf16x8 r;
  r[0] = f2bf(a.x * s); r[1] = f2bf(a.y * s);
  r[2] = f2bf(a.z * s); r[3] = f2bf(a.w * s);
  r[4] = f2bf(b.x * s); r[5] = f2bf(b.y * s);
  r[6] = f2bf(b.z * s); r[7] = f2bf(b.w * s);
  return r;
}

// One block = (b, h, 16-row q-tile). 4 waves; wave w owns t-cols [w*512, w*512+512).
// Single sweep: QK MFMA -> p = exp(blend) -> P(bf16) to LDS -> unnormalized PV MFMA.
// Then: cross-wave row-sum reduce; normalize+write attn from LDS; reduce+scale O.
// No barriers in the main loop.
__global__ __launch_bounds__(256) void fused_attn(
    const float* __restrict__ qp, const float* __restrict__ kp,
    const float* __restrict__ vp, const float* __restrict__ covp,
    const float* __restrict__ lamp, const int* __restrict__ maskp,
    float* __restrict__ outO, float* __restrict__ outA)
{
  __shared__ __align__(16) short Pl[16][PSTR];  // 65792 B -> 2 blocks/CU
  __shared__ float Ls[4][16];
  __shared__ float Lrow[16];

  const int tid  = threadIdx.x;
  const int wv   = tid >> 6;
  const int lane = tid & 63;
  const int quad = lane >> 4;
  const int l15  = lane & 15;

  // h in low bits: the 8 heads sharing a cov/mask tile are consecutive bids
  // (concurrent), so cov/mask stay L3-resident across their 8 uses.
  const int bid = blockIdx.x;
  const int h  = bid & 7;
  const int qt = (bid >> 3) & 127;
  const int b  = bid >> 10;

  const float lam   = lamp[h];
  const float w_qk  = 1.0f / (lam + 1.0f);
  const float w_cov = lam / (lam + 1.0f);
  const float qscale = w_qk * 0.125f;   // fold 1/TEMPERATURE and w_qk into Q

  const int q0 = qt * 16;
  const int bh = b * Hdim + h;

  const float* qbase = qp + ((size_t)bh * Sdim + q0) * Ddim;
  const float* kbase = kp + (size_t)bh * Sdim * Ddim;
  const float* vbase = vp + (size_t)bh * Sdim * Ddim;
  const float* covb  = covp + ((size_t)b * Sdim + q0) * Sdim;
  const int*   mb    = maskp + ((size_t)b * Sdim + q0) * Sdim;
  float* oA = outA + ((size_t)bh * Sdim + q0) * (size_t)Sdim;
  float* oO = outO + ((size_t)bh * Sdim + q0) * Ddim;

  // Q A-frag (16 rows x 64 k), pre-scaled: A[m=l15][k=quad*8+j]
  bf16x8 aq0, aq1;
  {
    const float* qr = qbase + l15 * Ddim + quad * 8;
    float4 x0 = *(const float4*)(qr);
    float4 x1 = *(const float4*)(qr + 4);
    aq0 = pack8(x0, x1, qscale);
    float4 y0 = *(const float4*)(qr + 32);
    float4 y1 = *(const float4*)(qr + 36);
    aq1 = pack8(y0, y1, qscale);
  }

  const int tbeg = wv * 512;
  const int tend = tbeg + 512;

  float lsum[4] = {0.f, 0.f, 0.f, 0.f};
  f32x4 oacc[4];
#pragma unroll
  for (int n = 0; n < 4; ++n) oacc[n] = (f32x4){0.f, 0.f, 0.f, 0.f};

#pragma unroll 2
  for (int t0 = tbeg; t0 < tend; t0 += 32) {
    // ---- QK^T for 32 t-cols ----
    f32x4 acc[2];
#pragma unroll
    for (int n = 0; n < 2; ++n) {
      const float* kr = kbase + (size_t)(t0 + n * 16 + l15) * Ddim + quad * 8;
      float4 x0 = *(const float4*)(kr);
      float4 x1 = *(const float4*)(kr + 4);
      float4 y0 = *(const float4*)(kr + 32);
      float4 y1 = *(const float4*)(kr + 36);
      bf16x8 b0 = pack8(x0, x1, 1.0f);
      bf16x8 b1 = pack8(y0, y1, 1.0f);
      f32x4 a = {0.f, 0.f, 0.f, 0.f};
      a = __builtin_amdgcn_mfma_f32_16x16x32_bf16(aq0, b0, a, 0, 0, 0);
      a = __builtin_amdgcn_mfma_f32_16x16x32_bf16(aq1, b1, a, 0, 0, 0);
      acc[n] = a;
    }

    // ---- V B-frags direct from global: B[k=t][n=d], lane: n=l15, k=quad*8+j ----
    bf16x8 bv[4];
#pragma unroll
    for (int nb = 0; nb < 4; ++nb) {
      const float* vcol = vbase + (size_t)(t0 + quad * 8) * Ddim + nb * 16 + l15;
#pragma unroll
      for (int j = 0; j < 8; ++j) bv[nb][j] = f2bf(vcol[j * Ddim]);
    }

    // ---- blend + mask + exp; stash unnormalized p ----
#pragma unroll
    for (int n = 0; n < 2; ++n) {
      const int col = t0 + n * 16 + l15;
#pragma unroll
      for (int r = 0; r < 4; ++r) {
        const int row = quad * 4 + r;           // C/D layout row
        float c = covb[row * Sdim + col];
        int   m = mb[row * Sdim + col];
        float logit = acc[n][r] + w_cov * c;
        float p = m ? __expf(logit) : 0.0f;     // |logit| small: no max-sub needed
        lsum[r] += p;
        Pl[row][col] = f2bf(p);
      }
    }

    // ---- PV accumulate (unnormalized): A-frag via LDS round-trip ----
    bf16x8 pa = *(const bf16x8*)&Pl[l15][t0 + quad * 8];
#pragma unroll
    for (int nb = 0; nb < 4; ++nb)
      oacc[nb] = __builtin_amdgcn_mfma_f32_16x16x32_bf16(pa, bv[nb], oacc[nb], 0, 0, 0);
  }

  // ---- cross-wave row-sum reduction ----
#pragma unroll
  for (int r = 0; r < 4; ++r) {
    float s = lsum[r];
    s += __shfl_xor(s, 1, 16);
    s += __shfl_xor(s, 2, 16);
    s += __shfl_xor(s, 4, 16);
    s += __shfl_xor(s, 8, 16);
    if (l15 == 0) Ls[wv][quad * 4 + r] = s;
  }
  __syncthreads();
  if (tid < 16) Lrow[tid] = 1.0f / (Ls[0][tid] + Ls[1][tid] + Ls[2][tid] + Ls[3][tid]);
  __syncthreads();

  // ---- normalize + write attn (each wave: its own 512-col slice, all 16 rows) ----
#pragma unroll 1
  for (int row = 0; row < 16; ++row) {
    const float rinv = Lrow[row];
    float* orow = oA + (size_t)row * Sdim;
#pragma unroll
    for (int cc = 0; cc < 2; ++cc) {
      const int c0 = tbeg + cc * 256 + lane * 4;
      bf16x4 pv = *(const bf16x4*)&Pl[row][c0];
      f32x4 o;
      o[0] = bf2f(pv[0]) * rinv;
      o[1] = bf2f(pv[1]) * rinv;
      o[2] = bf2f(pv[2]) * rinv;
      o[3] = bf2f(pv[3]) * rinv;
      __builtin_nontemporal_store(o, (f32x4*)&orow[c0]);
    }
  }
  __syncthreads();   // all P reads done; safe to alias

  // ---- O reduction across waves (alias P region), scale by 1/l, store ----
  float* Ored = (float*)&Pl[0][0];   // [4][64][16] f32 = 16 KB
#pragma unroll
  for (int nb = 0; nb < 4; ++nb)
#pragma unroll
    for (int r = 0; r < 4; ++r)
      Ored[((wv * 64 + lane) * 16) + nb * 4 + r] = oacc[nb][r];
  __syncthreads();
#pragma unroll
  for (int r = 0; r < 4; ++r) {
    float s = 0.f;
#pragma unroll
    for (int w2 = 0; w2 < 4; ++w2)
      s += Ored[((w2 * 64 + lane) * 16) + wv * 4 + r];
    const int row = quad * 4 + r;
    __builtin_nontemporal_store(s * Lrow[row], &oO[row * Ddim + wv * 16 + l15]);
  }
}

extern "C" void kernel_launch(void* const* d_in, const int* in_sizes, int n_in,
                              void* d_out, int out_size, void* d_ws, size_t ws_size,
                              hipStream_t stream) {
  const float* q    = (const float*)d_in[0];
  const float* k    = (const float*)d_in[1];
  const float* v    = (const float*)d_in[2];
  const float* cov  = (const float*)d_in[3];
  const float* lam  = (const float*)d_in[4];
  const int*   mask = (const int*)d_in[5];
  float* outO = (float*)d_out;
  float* outA = outO + (size_t)Bdim * Hdim * Sdim * Ddim;
  (void)d_ws; (void)ws_size;

  dim3 grid(Bdim * Hdim * (Sdim / 16));   // 2048 blocks
  fused_attn<<<grid, 256, 0, stream>>>(q, k, v, cov, lam, mask, outO, outA);
}

// Round 4
// 695.653 us; speedup vs baseline: 1.4856x; 1.0142x over previous
//
#include <hip/hip_runtime.h>

#define Bdim 2
#define Hdim 8
#define Sdim 2048
#define Ddim 64
#define PSTR 2056   // P row stride in shorts: +8 pad breaks 16-way bank aliasing
#define NW 8        // waves per block (512 threads)

typedef short bf16x8 __attribute__((ext_vector_type(8)));
typedef short bf16x4 __attribute__((ext_vector_type(4)));
typedef float f32x4 __attribute__((ext_vector_type(4)));

// float -> bf16 bits, round-to-nearest-even
static __device__ __forceinline__ short f2bf(float x) {
  unsigned u = __builtin_bit_cast(unsigned, x);
  unsigned r = (u + 0x7fffu + ((u >> 16) & 1u)) >> 16;
  return (short)r;
}
static __device__ __forceinline__ float bf2f(short x) {
  unsigned u = ((unsigned)(unsigned short)x) << 16;
  return __builtin_bit_cast(float, u);
}
static __device__ __forceinline__ bf16x8 pack8(float4 a, float4 b, float s) {
  bf16x8 r;
  r[0] = f2bf(a.x * s); r[1] = f2bf(a.y * s);
  r[2] = f2bf(a.z * s); r[3] = f2bf(a.w * s);
  r[4] = f2bf(b.x * s); r[5] = f2bf(b.y * s);
  r[6] = f2bf(b.z * s); r[7] = f2bf(b.w * s);
  return r;
}

// One block = (b, h, 16-row q-tile). 8 waves; wave w owns t-cols [w*256, w*256+256).
// 512 threads -> 2 blocks/CU = 16 waves/CU = 4 waves/SIMD (vs 2 at 256 threads):
// the main loop is latency-bound, occupancy is the lever.
// Single sweep: QK MFMA -> p = exp(blend) -> P(bf16) to LDS -> unnormalized PV MFMA.
// Then: cross-wave row-sum reduce; normalize+write attn from LDS; reduce+scale O.
__global__ __launch_bounds__(512, 4) void fused_attn(
    const float* __restrict__ qp, const float* __restrict__ kp,
    const float* __restrict__ vp, const float* __restrict__ covp,
    const float* __restrict__ lamp, const int* __restrict__ maskp,
    float* __restrict__ outO, float* __restrict__ outA)
{
  __shared__ __align__(16) short Pl[16][PSTR];  // 65792 B -> 2 blocks/CU
  __shared__ float Ls[NW][16];
  __shared__ float Lrow[16];

  const int tid  = threadIdx.x;
  const int wv   = tid >> 6;
  const int lane = tid & 63;
  const int quad = lane >> 4;
  const int l15  = lane & 15;

  // h in low bits: the 8 heads sharing a cov/mask tile are consecutive bids
  // (concurrent), so cov/mask stay L3-resident across their 8 uses.
  const int bid = blockIdx.x;
  const int h  = bid & 7;
  const int qt = (bid >> 3) & 127;
  const int b  = bid >> 10;

  const float lam   = lamp[h];
  const float w_qk  = 1.0f / (lam + 1.0f);
  const float w_cov = lam / (lam + 1.0f);
  const float qscale = w_qk * 0.125f;   // fold 1/TEMPERATURE and w_qk into Q

  const int q0 = qt * 16;
  const int bh = b * Hdim + h;

  const float* qbase = qp + ((size_t)bh * Sdim + q0) * Ddim;
  const float* kbase = kp + (size_t)bh * Sdim * Ddim;
  const float* vbase = vp + (size_t)bh * Sdim * Ddim;
  const float* covb  = covp + ((size_t)b * Sdim + q0) * Sdim;
  const int*   mb    = maskp + ((size_t)b * Sdim + q0) * Sdim;
  float* oA = outA + ((size_t)bh * Sdim + q0) * (size_t)Sdim;
  float* oO = outO + ((size_t)bh * Sdim + q0) * Ddim;

  // Q A-frag (16 rows x 64 k), pre-scaled: A[m=l15][k=quad*8+j]
  bf16x8 aq0, aq1;
  {
    const float* qr = qbase + l15 * Ddim + quad * 8;
    float4 x0 = *(const float4*)(qr);
    float4 x1 = *(const float4*)(qr + 4);
    aq0 = pack8(x0, x1, qscale);
    float4 y0 = *(const float4*)(qr + 32);
    float4 y1 = *(const float4*)(qr + 36);
    aq1 = pack8(y0, y1, qscale);
  }

  const int tbeg = wv * (Sdim / NW);
  const int tend = tbeg + (Sdim / NW);

  float lsum[4] = {0.f, 0.f, 0.f, 0.f};
  f32x4 oacc[4];
#pragma unroll
  for (int n = 0; n < 4; ++n) oacc[n] = (f32x4){0.f, 0.f, 0.f, 0.f};

#pragma unroll 2
  for (int t0 = tbeg; t0 < tend; t0 += 32) {
    // ---- QK^T for 32 t-cols ----
    f32x4 acc[2];
#pragma unroll
    for (int n = 0; n < 2; ++n) {
      const float* kr = kbase + (size_t)(t0 + n * 16 + l15) * Ddim + quad * 8;
      float4 x0 = *(const float4*)(kr);
      float4 x1 = *(const float4*)(kr + 4);
      float4 y0 = *(const float4*)(kr + 32);
      float4 y1 = *(const float4*)(kr + 36);
      bf16x8 b0 = pack8(x0, x1, 1.0f);
      bf16x8 b1 = pack8(y0, y1, 1.0f);
      f32x4 a = {0.f, 0.f, 0.f, 0.f};
      a = __builtin_amdgcn_mfma_f32_16x16x32_bf16(aq0, b0, a, 0, 0, 0);
      a = __builtin_amdgcn_mfma_f32_16x16x32_bf16(aq1, b1, a, 0, 0, 0);
      acc[n] = a;
    }

    // ---- V B-frags direct from global: B[k=t][n=d], lane: n=l15, k=quad*8+j ----
    bf16x8 bv[4];
#pragma unroll
    for (int nb = 0; nb < 4; ++nb) {
      const float* vcol = vbase + (size_t)(t0 + quad * 8) * Ddim + nb * 16 + l15;
#pragma unroll
      for (int j = 0; j < 8; ++j) bv[nb][j] = f2bf(vcol[j * Ddim]);
    }

    // ---- blend + mask + exp; stash unnormalized p ----
#pragma unroll
    for (int n = 0; n < 2; ++n) {
      const int col = t0 + n * 16 + l15;
#pragma unroll
      for (int r = 0; r < 4; ++r) {
        const int row = quad * 4 + r;           // C/D layout row
        float c = covb[row * Sdim + col];
        int   m = mb[row * Sdim + col];
        float logit = acc[n][r] + w_cov * c;
        float p = m ? __expf(logit) : 0.0f;     // |logit| small: no max-sub needed
        lsum[r] += p;
        Pl[row][col] = f2bf(p);
      }
    }

    // ---- PV accumulate (unnormalized): A-frag via LDS round-trip ----
    bf16x8 pa = *(const bf16x8*)&Pl[l15][t0 + quad * 8];
#pragma unroll
    for (int nb = 0; nb < 4; ++nb)
      oacc[nb] = __builtin_amdgcn_mfma_f32_16x16x32_bf16(pa, bv[nb], oacc[nb], 0, 0, 0);
  }

  // ---- cross-wave row-sum reduction ----
#pragma unroll
  for (int r = 0; r < 4; ++r) {
    float s = lsum[r];
    s += __shfl_xor(s, 1, 16);
    s += __shfl_xor(s, 2, 16);
    s += __shfl_xor(s, 4, 16);
    s += __shfl_xor(s, 8, 16);
    if (l15 == 0) Ls[wv][quad * 4 + r] = s;
  }
  __syncthreads();
  if (tid < 16) {
    float s = 0.f;
#pragma unroll
    for (int w2 = 0; w2 < NW; ++w2) s += Ls[w2][tid];
    Lrow[tid] = 1.0f / s;
  }
  __syncthreads();

  // ---- normalize + write attn (each wave: its own 256-col slice, all 16 rows) ----
#pragma unroll 1
  for (int row = 0; row < 16; ++row) {
    const float rinv = Lrow[row];
    float* orow = oA + (size_t)row * Sdim;
    const int c0 = tbeg + lane * 4;
    bf16x4 pv = *(const bf16x4*)&Pl[row][c0];
    f32x4 o;
    o[0] = bf2f(pv[0]) * rinv;
    o[1] = bf2f(pv[1]) * rinv;
    o[2] = bf2f(pv[2]) * rinv;
    o[3] = bf2f(pv[3]) * rinv;
    __builtin_nontemporal_store(o, (f32x4*)&orow[c0]);
  }
  __syncthreads();   // all P reads done; safe to alias

  // ---- O reduction across waves (alias P region), scale by 1/l, store ----
  float* Ored = (float*)&Pl[0][0];   // [NW][64][16] f32 = 32 KB, fits in P alias
#pragma unroll
  for (int nb = 0; nb < 4; ++nb)
#pragma unroll
    for (int r = 0; r < 4; ++r)
      Ored[((wv * 64 + lane) * 16) + nb * 4 + r] = oacc[nb][r];
  __syncthreads();
  if (wv < 4) {
#pragma unroll
    for (int r = 0; r < 4; ++r) {
      float s = 0.f;
#pragma unroll
      for (int w2 = 0; w2 < NW; ++w2)
        s += Ored[((w2 * 64 + lane) * 16) + wv * 4 + r];
      const int row = quad * 4 + r;
      __builtin_nontemporal_store(s * Lrow[row], &oO[row * Ddim + wv * 16 + l15]);
    }
  }
}

extern "C" void kernel_launch(void* const* d_in, const int* in_sizes, int n_in,
                              void* d_out, int out_size, void* d_ws, size_t ws_size,
                              hipStream_t stream) {
  const float* q    = (const float*)d_in[0];
  const float* k    = (const float*)d_in[1];
  const float* v    = (const float*)d_in[2];
  const float* cov  = (const float*)d_in[3];
  const float* lam  = (const float*)d_in[4];
  const int*   mask = (const int*)d_in[5];
  float* outO = (float*)d_out;
  float* outA = outO + (size_t)Bdim * Hdim * Sdim * Ddim;
  (void)d_ws; (void)ws_size;

  dim3 grid(Bdim * Hdim * (Sdim / 16));   // 2048 blocks x 512 threads
  fused_attn<<<grid, 512, 0, stream>>>(q, k, v, cov, lam, mask, outO, outA);
}